// Round 4
// baseline (84548.926 us; speedup 1.0000x reference)
//
#include <hip/hip_runtime.h>

#define HH 128      // hidden size
#define G4 512      // 4*HH gates
#define TT 102400   // sequence length
#define BB 8        // batch
// stage A/C LDS layout: 8 segments of 16 floats, stride 20 (bank-clean)
#define SEG20 20
#define HBUF 160
// stage B (quad r=4) layout: 4 segments of 32 floats, stride 36
#define SEGP 36

typedef float v2f __attribute__((ext_vector_type(2)));

// ---------------- DPP cross-lane adds (VALU pipe, not LDS) -----------------
template<int CTRL>
__device__ __forceinline__ float dpp_add(float v) {
    int p = __builtin_amdgcn_update_dpp(0, __float_as_int(v), CTRL, 0xF, 0xF, true);
    return v + __int_as_float(p);
}
// 0xB1 = quad_perm xor1 ; 0x4E = quad_perm xor2 ; 0x141 = row_half_mirror
// (lane ^7 within 8; equals xor4 once values are quad-uniform)

// ---------------- fast activations (raw v_rcp = 1 ulp; saturate cleanly) ---
__device__ __forceinline__ float sig_f(float x) {
    return __builtin_amdgcn_rcpf(1.0f + __expf(-x));
}
__device__ __forceinline__ float tanh_f(float x) {
    return fmaf(2.0f, __builtin_amdgcn_rcpf(1.0f + __expf(-2.0f * x)), -1.0f);
}

// ---------------- r=8 chain math: 8 rows/thread, k=16/thread ---------------
// group = 8 lanes (g8 = t>>3, j = t&7); rows r=0..3 -> cellA+128r,
// r=4..7 -> cellB+128(r-4); lane j covers k in [16j, 16j+16).
__device__ __forceinline__ void load_w8(const float* __restrict__ W,
                                        int cA, int cB, int j, v2f w[8][8]) {
#pragma unroll
    for (int r = 0; r < 8; ++r) {
        int row = (r < 4) ? (cA + 128 * r) : (cB + 128 * (r - 4));
        const v2f* rp = (const v2f*)(W + (size_t)row * HH + 16 * j);
#pragma unroll
        for (int p = 0; p < 8; ++p) w[r][p] = rp[p];
    }
}

// full 128-dots of the 8 rows, result replicated across the 8-lane group
__device__ __forceinline__ void dot8(const v2f w[8][8],
                                     const float* __restrict__ hseg,
                                     float s[8]) {
    const v2f* h2 = (const v2f*)hseg;       // 4x ds_read_b128
    v2f acc[8];
#pragma unroll
    for (int r = 0; r < 8; ++r) acc[r] = (v2f){0.f, 0.f};
#pragma unroll
    for (int p = 0; p < 8; ++p) {
        v2f hv = h2[p];
#pragma unroll
        for (int r = 0; r < 8; ++r)
            acc[r] = __builtin_elementwise_fma(hv, w[r][p], acc[r]);  // v_pk_fma_f32
    }
#pragma unroll
    for (int r = 0; r < 8; ++r) {
        float t = acc[r].x + acc[r].y;
        t = dpp_add<0xB1>(t);
        t = dpp_add<0x4E>(t);
        t = dpp_add<0x141>(t);
        s[r] = t;
    }
}

// ---------------- stage-B math (r=4 quad, off critical path) ---------------
__device__ __forceinline__ void load_w4(const float* __restrict__ W,
                                        int q, int l, float4 w[4][8]) {
#pragma unroll
    for (int m = 0; m < 4; ++m) {
        const float4* rp = (const float4*)(W + (size_t)(q + 128 * m) * HH + 32 * l);
#pragma unroll
        for (int r = 0; r < 8; ++r) w[m][r] = rp[r];
    }
}
__device__ __forceinline__ void quad_dot4(const float4 w[4][8],
                                          const float* __restrict__ hseg,
                                          float s[4]) {
    const float4* h4 = (const float4*)hseg;
    float4 a0 = {0,0,0,0}, a1 = {0,0,0,0}, a2 = {0,0,0,0}, a3 = {0,0,0,0};
#pragma unroll
    for (int r = 0; r < 8; ++r) {
        float4 hv = h4[r];
        a0.x = fmaf(hv.x, w[0][r].x, a0.x); a0.y = fmaf(hv.y, w[0][r].y, a0.y);
        a0.z = fmaf(hv.z, w[0][r].z, a0.z); a0.w = fmaf(hv.w, w[0][r].w, a0.w);
        a1.x = fmaf(hv.x, w[1][r].x, a1.x); a1.y = fmaf(hv.y, w[1][r].y, a1.y);
        a1.z = fmaf(hv.z, w[1][r].z, a1.z); a1.w = fmaf(hv.w, w[1][r].w, a1.w);
        a2.x = fmaf(hv.x, w[2][r].x, a2.x); a2.y = fmaf(hv.y, w[2][r].y, a2.y);
        a2.z = fmaf(hv.z, w[2][r].z, a2.z); a2.w = fmaf(hv.w, w[2][r].w, a2.w);
        a3.x = fmaf(hv.x, w[3][r].x, a3.x); a3.y = fmaf(hv.y, w[3][r].y, a3.y);
        a3.z = fmaf(hv.z, w[3][r].z, a3.z); a3.w = fmaf(hv.w, w[3][r].w, a3.w);
    }
    s[0] = (a0.x + a0.y) + (a0.z + a0.w);
    s[1] = (a1.x + a1.y) + (a1.z + a1.w);
    s[2] = (a2.x + a2.y) + (a2.z + a2.w);
    s[3] = (a3.x + a3.y) + (a3.z + a3.w);
#pragma unroll
    for (int m = 0; m < 4; ++m) {
        s[m] = dpp_add<0xB1>(s[m]);
        s[m] = dpp_add<0x4E>(s[m]);
    }
}

// ---------------------------------------------------------------------------
// One pipeline slot: blocks 0..7  = stage A (layer0 chain, chunk c)
//                    blocks 8..15 = stage C (layer1 chain, chunk c-2)
//                    blocks 16..79= stage B (xp1 = Wih1@h1 GEMM, chunk c-1)
// ---------------------------------------------------------------------------
__global__ void
__attribute__((amdgpu_flat_work_group_size(512, 512), amdgpu_waves_per_eu(2, 2)))
lstm_slot_kernel(
    const float* __restrict__ x,
    const float* __restrict__ Wih0, const float* __restrict__ Whh0,
    const float* __restrict__ bih0, const float* __restrict__ bhh0,
    const float* __restrict__ Wih1, const float* __restrict__ Whh1,
    const float* __restrict__ bih1, const float* __restrict__ bhh1,
    float* __restrict__ h1s, float* __restrict__ c1s,
    float* __restrict__ h2s, float* __restrict__ c2s,
    double* __restrict__ pooled,
    float* __restrict__ h1ring,   // [2][B][chunkT][HH]
    float* __restrict__ xpring,   // [2][B][chunkT][HH][4]  (t, cell, gate)
    int c, int chunkT, int nchunks)
{
    __shared__ __align__(16) float h_s[2][HBUF];
    const int t = threadIdx.x;

    if (blockIdx.x < 16) {
        // =============== chain stages (A: layer0, C: layer1) ===============
        const bool isA = (blockIdx.x < 8);
        const int cc = isA ? c : (c - 2);
        if (cc < 0 || cc >= nchunks) return;
        const int b = blockIdx.x & 7;
        const int g8 = t >> 3, j = t & 7;
        const int cA = 2 * g8, cB = cA + 1;
        const bool lo = (j < 4);
        const int myc  = lo ? cA : cB;
        const int segw = (myc >> 4) * SEG20 + (myc & 15);
        const bool writer = ((j & 3) == 0);

        v2f w[8][8];
        load_w8(isA ? Whh0 : Whh1, cA, cB, j, w);

        float bias4[4], wih4[4];
        if (isA) {
#pragma unroll
            for (int m = 0; m < 4; ++m) {
                int r = myc + 128 * m;
                bias4[m] = bih0[r] + bhh0[r];
                wih4[m]  = Wih0[r];
            }
        }
        float* hst = isA ? h1s : h2s;
        float* cst = isA ? c1s : c2s;
        float c_reg = cst[b * HH + myc];
        if (t < HH) h_s[0][(t >> 4) * SEG20 + (t & 15)] = hst[b * HH + t];

        float* ringp = h1ring + ((size_t)((c & 1) * BB + b)) * (size_t)chunkT * HH;
        const float4* xb4 = (const float4*)(x + (size_t)b * TT + (size_t)cc * chunkT);
        const float4* xpq = (const float4*)(xpring
            + ((size_t)((cc & 1) * BB + b)) * (size_t)chunkT * G4);

        const int nt4 = chunkT >> 2;
        float4 xq = isA ? xb4[0] : (float4){0, 0, 0, 0};
        float4 xc[4];
        if (!isA) {
#pragma unroll
            for (int u = 0; u < 4; ++u) xc[u] = xpq[(size_t)u * HH + myc];
        }
        double pacc = 0.0;
        float h = 0.f;
        __syncthreads();

        for (int t4 = 0; t4 < nt4; ++t4) {
            float4 xqn = {0, 0, 0, 0};
            float4 xn[4];
            if (isA) {
                if (t4 + 1 < nt4) xqn = xb4[t4 + 1];
            } else if (t4 + 1 < nt4) {
#pragma unroll
                for (int u = 0; u < 4; ++u)
                    xn[u] = xpq[(size_t)(t4 * 4 + 4 + u) * HH + myc];
            } else {
#pragma unroll
                for (int u = 0; u < 4; ++u) xn[u] = (float4){0, 0, 0, 0};
            }
#pragma unroll
            for (int u = 0; u < 4; ++u) {
                const int buf = u & 1;
                float s[8];
                dot8(w, &h_s[buf][j * SEG20], s);
                float s0 = lo ? s[0] : s[4];
                float s1 = lo ? s[1] : s[5];
                float s2 = lo ? s[2] : s[6];
                float s3 = lo ? s[3] : s[7];
                float i_, f_, g_, o_;
                if (isA) {
                    float xt = (u == 0) ? xq.x : (u == 1) ? xq.y : (u == 2) ? xq.z : xq.w;
                    i_ = sig_f (fmaf(xt, wih4[0], s0 + bias4[0]));
                    f_ = sig_f (fmaf(xt, wih4[1], s1 + bias4[1]));
                    g_ = tanh_f(fmaf(xt, wih4[2], s2 + bias4[2]));
                    o_ = sig_f (fmaf(xt, wih4[3], s3 + bias4[3]));
                } else {
                    i_ = sig_f (s0 + xc[u].x);
                    f_ = sig_f (s1 + xc[u].y);
                    g_ = tanh_f(s2 + xc[u].z);
                    o_ = sig_f (s3 + xc[u].w);
                }
                c_reg = fmaf(f_, c_reg, i_ * g_);
                h = o_ * tanh_f(c_reg);
                if (writer) {
                    h_s[buf ^ 1][segw] = h;
                    if (isA) ringp[(size_t)(t4 * 4 + u) * HH + myc] = h;
                }
                if (!isA) pacc += (double)h;
                __syncthreads();
            }
            xq = xqn;
            if (!isA) {
#pragma unroll
                for (int u = 0; u < 4; ++u) xc[u] = xn[u];
            }
        }
        if (writer) {
            cst[b * HH + myc] = c_reg;
            hst[b * HH + myc] = h;
            if (!isA) pooled[b * HH + myc] += pacc;
        }

    } else {
        // ---------------- stage B: xp1 = Wih1 @ h1 + bias, chunk c-1 -------
        const int bc = c - 1;
        if (bc < 0 || bc >= nchunks) return;
        const int ib = blockIdx.x - 16;     // 0..63
        const int bb = ib >> 3;             // batch
        const int sl = ib & 7;              // t-slice (stride 8)
        const int q = t >> 2, l = t & 3;
        float4 w[4][8];
        load_w4(Wih1, q, l, w);
        float bias4[4];
#pragma unroll
        for (int m = 0; m < 4; ++m) {
            int r = q + 128 * m;
            bias4[m] = bih1[r] + bhh1[r];
        }
        const float* hrp = h1ring + ((size_t)((bc & 1) * BB + bb)) * (size_t)chunkT * HH;
        float* xpw = xpring + ((size_t)((bc & 1) * BB + bb)) * (size_t)chunkT * G4;
        if (t < HH) h_s[0][(t >> 5) * SEGP + (t & 31)] = hrp[(size_t)sl * HH + t];
        __syncthreads();
        int p = 0;
        for (int tt = sl; tt < chunkT; tt += 8) {
            int ttn = tt + 8;
            bool pf = (t < HH) && (ttn < chunkT);
            float hn = 0.f;
            if (pf) hn = hrp[(size_t)ttn * HH + t];     // prefetch next tile
            float s[4];
            quad_dot4(w, &h_s[p][l * SEGP], s);
            if (pf) h_s[p ^ 1][(t >> 5) * SEGP + (t & 31)] = hn;
            float v0 = s[0] + bias4[0], v1 = s[1] + bias4[1];
            float v2 = s[2] + bias4[2], v3 = s[3] + bias4[3];
            // lane l writes gate l of cell q: addr = tt*512 + q*4 + l = tt*512 + t
            float val = (l == 0) ? v0 : (l == 1) ? v1 : (l == 2) ? v2 : v3;
            xpw[(size_t)tt * G4 + t] = val;
            __syncthreads();
            p ^= 1;
        }
    }
}

// ---------------- head: mean-pool (done) -> FC+ReLU -> FC ------------------
__global__ void head_kernel(const double* __restrict__ pooled,
                            const float* __restrict__ fcW1, const float* __restrict__ fcb1,
                            const float* __restrict__ fcW2, const float* __restrict__ fcb2,
                            float* __restrict__ out)
{
    __shared__ float p_s[HH];
    __shared__ float hid_s[64];
    const int b = blockIdx.x, t = threadIdx.x;
    if (t < HH) p_s[t] = (float)(pooled[b * HH + t] * (1.0 / (double)TT));
    __syncthreads();
    if (t < 64) {
        float acc = fcb1[t];
#pragma unroll 8
        for (int k = 0; k < HH; ++k) acc = fmaf(p_s[k], fcW1[t * HH + k], acc);
        hid_s[t] = fmaxf(acc, 0.f);
    }
    __syncthreads();
    if (t < 11) {
        float acc = fcb2[t];
#pragma unroll
        for (int k = 0; k < 64; ++k) acc = fmaf(hid_s[k], fcW2[t * 64 + k], acc);
        out[b * 11 + t] = acc;
    }
}

// ---------------------------------------------------------------------------
extern "C" void kernel_launch(void* const* d_in, const int* in_sizes, int n_in,
                              void* d_out, int out_size, void* d_ws, size_t ws_size,
                              hipStream_t stream)
{
    const float* x    = (const float*)d_in[0];
    const float* Wih0 = (const float*)d_in[1];
    const float* Whh0 = (const float*)d_in[2];
    const float* bih0 = (const float*)d_in[3];
    const float* bhh0 = (const float*)d_in[4];
    const float* Wih1 = (const float*)d_in[5];
    const float* Whh1 = (const float*)d_in[6];
    const float* bih1 = (const float*)d_in[7];
    const float* bhh1 = (const float*)d_in[8];
    const float* fcW1 = (const float*)d_in[9];
    const float* fcb1 = (const float*)d_in[10];
    const float* fcW2 = (const float*)d_in[11];
    const float* fcb2 = (const float*)d_in[12];
    float* out = (float*)d_out;

    // ---- workspace layout ----
    char* wsp = (char*)d_ws;
    float*  h1s    = (float*) (wsp + 0);
    float*  c1s    = (float*) (wsp + 4096);
    float*  h2s    = (float*) (wsp + 8192);
    float*  c2s    = (float*) (wsp + 12288);
    double* pooled = (double*)(wsp + 16384);          // 8 KB
    const size_t STATE_BYTES = 24576;

    // chunk size: biggest candidate (multiple of 8, divides TT) whose
    // double-buffered rings fit: per-t bytes = 2*8*128*4 + 2*8*512*4 = 40960
    static const int cands[] = {3200, 1600, 800, 400, 160, 80, 40, 8};
    int chunkT = 8;
    for (int i = 0; i < 8; ++i) {
        size_t need = STATE_BYTES + (size_t)40960 * (size_t)cands[i];
        if (need <= ws_size) { chunkT = cands[i]; break; }
    }
    const int nchunks = TT / chunkT;

    float* h1ring = (float*)(wsp + STATE_BYTES);
    float* xpring = (float*)(wsp + STATE_BYTES + (size_t)2 * BB * chunkT * HH * 4);

    // zero persistent state (h/c/pooled); ws is re-poisoned before every call
    hipMemsetAsync(d_ws, 0, STATE_BYTES, stream);

    // pipeline: slot c runs A(c) || B(c-1) || C(c-2)
    const int nslots = nchunks + 2;
    for (int c = 0; c < nslots; ++c) {
        lstm_slot_kernel<<<80, 512, 0, stream>>>(
            x, Wih0, Whh0, bih0, bhh0, Wih1, Whh1, bih1, bhh1,
            h1s, c1s, h2s, c2s, pooled, h1ring, xpring,
            c, chunkT, nchunks);
    }
    head_kernel<<<BB, 128, 0, stream>>>(pooled, fcW1, fcb1, fcW2, fcb2, out);
}

// Round 5
// 65180.652 us; speedup vs baseline: 1.2971x; 1.2971x over previous
//
#include <hip/hip_runtime.h>

#define HH 128      // hidden size
#define G4 512      // 4*HH gates
#define TT 102400   // sequence length
#define BB 8        // batch
#define SEGP 36     // stage-B fp32 padded k-segment stride (floats)

typedef _Float16 v2h __attribute__((ext_vector_type(2)));
typedef _Float16 v8h __attribute__((ext_vector_type(8)));

#if defined(__has_builtin)
#if __has_builtin(__builtin_amdgcn_fdot2)
#define HAVE_FDOT2 1
#endif
#endif
#ifdef HAVE_FDOT2
#define FDOT2(a, b, c) __builtin_amdgcn_fdot2((a), (b), (c), false)
#else
__device__ __forceinline__ float fdot2_fb(v2h a, v2h b, float c) {
    return fmaf((float)a[0], (float)b[0], fmaf((float)a[1], (float)b[1], c));
}
#define FDOT2(a, b, c) fdot2_fb((a), (b), (c))
#endif

// ---------------- DPP quad butterfly (VALU pipe) ---------------------------
template<int CTRL>
__device__ __forceinline__ float dpp_add(float v) {
    int p = __builtin_amdgcn_update_dpp(0, __float_as_int(v), CTRL, 0xF, 0xF, true);
    return v + __int_as_float(p);
}
// 0xB1 = quad_perm xor1 ; 0x4E = quad_perm xor2

// ---------------- fast activations (raw v_rcp = 1 ulp; saturate cleanly) ---
__device__ __forceinline__ float sig_f(float x) {
    return __builtin_amdgcn_rcpf(1.0f + __expf(-x));
}
__device__ __forceinline__ float tanh_f(float x) {
    return fmaf(2.0f, __builtin_amdgcn_rcpf(1.0f + __expf(-2.0f * x)), -1.0f);
}

// ---------------- chain dot: 8 rows/thread, fp16, k=32/lane ----------------
// quad Q owns cells {2Q, 2Q+1}; row r = 2Q + (r&1) + 128*(r>>1).
// lane l covers k in [32l, 32l+32). Result s[0..7] = full 128-dots,
// identical across the quad (DPP butterfly).
__device__ __forceinline__ void dot8h(const v2h w[8][16],
                                      const _Float16* __restrict__ hbuf,
                                      int l, float s[8]) {
    const v8h* h8 = (const v8h*)(hbuf + 32 * l);   // 16B-aligned (64B*l)
    v8h hv[4];
#pragma unroll
    for (int i = 0; i < 4; ++i) hv[i] = h8[i];     // 4x ds_read_b128 (broadcast)
    float acc[8];
#pragma unroll
    for (int r = 0; r < 8; ++r) acc[r] = 0.f;
#pragma unroll
    for (int i = 0; i < 16; ++i) {
        v2h hp = (v2h){hv[i >> 2][2 * (i & 3)], hv[i >> 2][2 * (i & 3) + 1]};
#pragma unroll
        for (int r = 0; r < 8; ++r)
            acc[r] = FDOT2(w[r][i], hp, acc[r]);   // v_dot2_f32_f16
    }
#pragma unroll
    for (int r = 0; r < 8; ++r) {
        float v = acc[r];
        v = dpp_add<0xB1>(v);
        v = dpp_add<0x4E>(v);
        s[r] = v;
    }
}

// ---------------- stage-B math (fp32, off critical path) -------------------
__device__ __forceinline__ void load_w4(const float* __restrict__ W,
                                        int q, int l, float4 w[4][8]) {
#pragma unroll
    for (int m = 0; m < 4; ++m) {
        const float4* rp = (const float4*)(W + (size_t)(q + 128 * m) * HH + 32 * l);
#pragma unroll
        for (int r = 0; r < 8; ++r) w[m][r] = rp[r];
    }
}
__device__ __forceinline__ void quad_dot4(const float4 w[4][8],
                                          const float* __restrict__ hseg,
                                          float s[4]) {
    const float4* h4 = (const float4*)hseg;
    float4 a0 = {0,0,0,0}, a1 = {0,0,0,0}, a2 = {0,0,0,0}, a3 = {0,0,0,0};
#pragma unroll
    for (int r = 0; r < 8; ++r) {
        float4 hv = h4[r];
        a0.x = fmaf(hv.x, w[0][r].x, a0.x); a0.y = fmaf(hv.y, w[0][r].y, a0.y);
        a0.z = fmaf(hv.z, w[0][r].z, a0.z); a0.w = fmaf(hv.w, w[0][r].w, a0.w);
        a1.x = fmaf(hv.x, w[1][r].x, a1.x); a1.y = fmaf(hv.y, w[1][r].y, a1.y);
        a1.z = fmaf(hv.z, w[1][r].z, a1.z); a1.w = fmaf(hv.w, w[1][r].w, a1.w);
        a2.x = fmaf(hv.x, w[2][r].x, a2.x); a2.y = fmaf(hv.y, w[2][r].y, a2.y);
        a2.z = fmaf(hv.z, w[2][r].z, a2.z); a2.w = fmaf(hv.w, w[2][r].w, a2.w);
        a3.x = fmaf(hv.x, w[3][r].x, a3.x); a3.y = fmaf(hv.y, w[3][r].y, a3.y);
        a3.z = fmaf(hv.z, w[3][r].z, a3.z); a3.w = fmaf(hv.w, w[3][r].w, a3.w);
    }
    s[0] = (a0.x + a0.y) + (a0.z + a0.w);
    s[1] = (a1.x + a1.y) + (a1.z + a1.w);
    s[2] = (a2.x + a2.y) + (a2.z + a2.w);
    s[3] = (a3.x + a3.y) + (a3.z + a3.w);
#pragma unroll
    for (int m = 0; m < 4; ++m) {
        s[m] = dpp_add<0xB1>(s[m]);
        s[m] = dpp_add<0x4E>(s[m]);
    }
}

// ---------------------------------------------------------------------------
// One pipeline slot (all blocks 256 threads):
//   blocks 0..7    = stage A (layer0 chain, chunk c)      — 1 wave/SIMD
//   blocks 8..15   = stage C (layer1 chain, chunk c-2)    — 1 wave/SIMD
//   blocks 16..143 = stage B (xp1 GEMM, chunk c-1): 8 batch x 8 t-slice x 2 cell-half
// Stages independent within a launch; stream order gives producer->consumer
// ordering across launches (kernel-boundary release/acquire).
// ---------------------------------------------------------------------------
__global__ void __launch_bounds__(256, 1)
lstm_slot_kernel(
    const float* __restrict__ x,
    const float* __restrict__ Wih0, const float* __restrict__ Whh0,
    const float* __restrict__ bih0, const float* __restrict__ bhh0,
    const float* __restrict__ Wih1, const float* __restrict__ Whh1,
    const float* __restrict__ bih1, const float* __restrict__ bhh1,
    float* __restrict__ h1s, float* __restrict__ c1s,
    float* __restrict__ h2s, float* __restrict__ c2s,
    double* __restrict__ pooled,
    _Float16* __restrict__ h1ring,  // [2][B][chunkT][HH]   fp16
    float* __restrict__ xpring,     // [2][B][chunkT][HH][4] (t,cell,gate) fp32
    int c, int chunkT, int nchunks)
{
    // shared: chain uses 2x128 halfs (512B); stage B uses 2x144 floats (1152B)
    __shared__ __align__(16) unsigned char smem[2 * 4 * SEGP * 4];
    const int t = threadIdx.x;

    if (blockIdx.x < 16) {
        // =============== chain stages (A: layer0, C: layer1) ===============
        const bool isA = (blockIdx.x < 8);
        const int cc = isA ? c : (c - 2);
        if (cc < 0 || cc >= nchunks) return;
        const int b = blockIdx.x & 7;
        const int Q = t >> 2;            // quad 0..63 -> cells {2Q, 2Q+1}
        const int l = t & 3;             // k-quarter lane
        const int p = l & 1;             // which cell of the pair this lane runs
        const int myc = 2 * Q + p;
        const bool writer = (l < 2);     // lanes 0,1 write cells 2Q, 2Q+1

        _Float16* hh = (_Float16*)smem;  // [2][HH]

        // weights fp32 -> fp16 registers (one-time per slot)
        v2h w[8][16];
        const float* Wl = isA ? Whh0 : Whh1;
#pragma unroll
        for (int r = 0; r < 8; ++r) {
            int row = 2 * Q + (r & 1) + 128 * (r >> 1);
            const float4* rp = (const float4*)(Wl + (size_t)row * HH + 32 * l);
#pragma unroll
            for (int i = 0; i < 8; ++i) {
                float4 f = rp[i];
                w[r][2 * i]     = (v2h){(_Float16)f.x, (_Float16)f.y};
                w[r][2 * i + 1] = (v2h){(_Float16)f.z, (_Float16)f.w};
            }
        }
        float bias4[4], wih4[4];
#pragma unroll
        for (int m = 0; m < 4; ++m) {
            int r = myc + 128 * m;
            if (isA) { bias4[m] = bih0[r] + bhh0[r]; wih4[m] = Wih0[r]; }
            else     { bias4[m] = 0.f;               wih4[m] = 0.f;     }
        }
        float* hst = isA ? h1s : h2s;
        float* cst = isA ? c1s : c2s;
        float c_reg = cst[b * HH + myc];
        if (t < HH) hh[t] = (_Float16)hst[b * HH + t];

        _Float16* ringp = h1ring + ((size_t)((c & 1) * BB + b)) * (size_t)chunkT * HH;
        const float4* xb4 = (const float4*)(x + (size_t)b * TT + (size_t)cc * chunkT);
        const float4* xpq = (const float4*)(xpring
            + ((size_t)((cc & 1) * BB + b)) * (size_t)chunkT * G4);

        const int nt4 = chunkT >> 2;
        float4 xq = isA ? xb4[0] : (float4){0, 0, 0, 0};
        float4 xc[4];
        if (!isA) {
#pragma unroll
            for (int u = 0; u < 4; ++u) xc[u] = xpq[(size_t)u * HH + myc];
        }
        double pacc = 0.0;
        float h = 0.f;
        __syncthreads();

        for (int t4 = 0; t4 < nt4; ++t4) {
            float4 xqn = {0, 0, 0, 0};
            float4 xn[4];
            if (isA) {
                if (t4 + 1 < nt4) xqn = xb4[t4 + 1];
            } else if (t4 + 1 < nt4) {
#pragma unroll
                for (int u = 0; u < 4; ++u)
                    xn[u] = xpq[(size_t)(t4 * 4 + 4 + u) * HH + myc];
            } else {
#pragma unroll
                for (int u = 0; u < 4; ++u) xn[u] = (float4){0, 0, 0, 0};
            }
#pragma unroll
            for (int u = 0; u < 4; ++u) {
                const int buf = u & 1;                 // static parity
                float s[8];
                dot8h(w, hh + buf * HH, l, s);
                // select this lane's cell (p) from the pair
                float s0 = p ? s[1] : s[0];
                float s1 = p ? s[3] : s[2];
                float s2 = p ? s[5] : s[4];
                float s3 = p ? s[7] : s[6];
                float i_, f_, g_, o_;
                if (isA) {
                    float xt = (u == 0) ? xq.x : (u == 1) ? xq.y : (u == 2) ? xq.z : xq.w;
                    i_ = sig_f (fmaf(xt, wih4[0], s0 + bias4[0]));
                    f_ = sig_f (fmaf(xt, wih4[1], s1 + bias4[1]));
                    g_ = tanh_f(fmaf(xt, wih4[2], s2 + bias4[2]));
                    o_ = sig_f (fmaf(xt, wih4[3], s3 + bias4[3]));
                } else {
                    i_ = sig_f (s0 + xc[u].x);
                    f_ = sig_f (s1 + xc[u].y);
                    g_ = tanh_f(s2 + xc[u].z);
                    o_ = sig_f (s3 + xc[u].w);
                }
                c_reg = fmaf(f_, c_reg, i_ * g_);
                h = o_ * tanh_f(c_reg);
                _Float16 hhv = (_Float16)h;            // RNE
                if (writer) {
                    hh[(buf ^ 1) * HH + myc] = hhv;
                    if (isA) ringp[(size_t)(t4 * 4 + u) * HH + myc] = hhv;
                }
                if (!isA) pacc += (double)h;
                __syncthreads();
            }
            xq = xqn;
            if (!isA) {
#pragma unroll
                for (int u = 0; u < 4; ++u) xc[u] = xn[u];
            }
        }
        if (writer) {
            cst[b * HH + myc] = c_reg;
            hst[b * HH + myc] = h;
            if (!isA) pooled[b * HH + myc] += pacc;
        }

    } else {
        // ---------------- stage B: xp1 = Wih1 @ h1 + bias, chunk c-1 -------
        const int bc = c - 1;
        if (bc < 0 || bc >= nchunks) return;
        const int ib = blockIdx.x - 16;       // 0..127
        const int bb = ib >> 4;               // batch
        const int sl = (ib >> 1) & 7;         // t-slice (stride 8)
        const int qh = (ib & 1) * 64;         // cell half
        const int q = (t >> 2) + qh;          // cell 0..127
        const int l = t & 3;
        float* hs = (float*)smem;             // [2][4*SEGP]
        float4 w[4][8];
        load_w4(Wih1, q, l, w);
        float bias4[4];
#pragma unroll
        for (int m = 0; m < 4; ++m) {
            int r = q + 128 * m;
            bias4[m] = bih1[r] + bhh1[r];
        }
        const _Float16* hrp = h1ring
            + ((size_t)((bc & 1) * BB + bb)) * (size_t)chunkT * HH;
        float* xpw = xpring + ((size_t)((bc & 1) * BB + bb)) * (size_t)chunkT * G4;
        if (t < HH)
            hs[(t >> 5) * SEGP + (t & 31)] = (float)hrp[(size_t)sl * HH + t];
        __syncthreads();
        int pb = 0;
        for (int tt = sl; tt < chunkT; tt += 8) {
            int ttn = tt + 8;
            bool pf = (t < HH) && (ttn < chunkT);
            float hn = 0.f;
            if (pf) hn = (float)hrp[(size_t)ttn * HH + t];   // prefetch
            float s[4];
            quad_dot4(w, &hs[pb * 4 * SEGP + l * SEGP], s);
            if (pf) hs[(pb ^ 1) * 4 * SEGP + (t >> 5) * SEGP + (t & 31)] = hn;
            float v0 = s[0] + bias4[0], v1 = s[1] + bias4[1];
            float v2 = s[2] + bias4[2], v3 = s[3] + bias4[3];
            float val = (l == 0) ? v0 : (l == 1) ? v1 : (l == 2) ? v2 : v3;
            xpw[(size_t)tt * G4 + q * 4 + l] = val;          // coalesced
            __syncthreads();
            pb ^= 1;
        }
    }
}

// ---------------- head: mean-pool (done) -> FC+ReLU -> FC ------------------
__global__ void head_kernel(const double* __restrict__ pooled,
                            const float* __restrict__ fcW1, const float* __restrict__ fcb1,
                            const float* __restrict__ fcW2, const float* __restrict__ fcb2,
                            float* __restrict__ out)
{
    __shared__ float p_s[HH];
    __shared__ float hid_s[64];
    const int b = blockIdx.x, t = threadIdx.x;
    if (t < HH) p_s[t] = (float)(pooled[b * HH + t] * (1.0 / (double)TT));
    __syncthreads();
    if (t < 64) {
        float acc = fcb1[t];
#pragma unroll 8
        for (int k = 0; k < HH; ++k) acc = fmaf(p_s[k], fcW1[t * HH + k], acc);
        hid_s[t] = fmaxf(acc, 0.f);
    }
    __syncthreads();
    if (t < 11) {
        float acc = fcb2[t];
#pragma unroll
        for (int k = 0; k < 64; ++k) acc = fmaf(hid_s[k], fcW2[t * 64 + k], acc);
        out[b * 11 + t] = acc;
    }
}

// ---------------------------------------------------------------------------
extern "C" void kernel_launch(void* const* d_in, const int* in_sizes, int n_in,
                              void* d_out, int out_size, void* d_ws, size_t ws_size,
                              hipStream_t stream)
{
    const float* x    = (const float*)d_in[0];
    const float* Wih0 = (const float*)d_in[1];
    const float* Whh0 = (const float*)d_in[2];
    const float* bih0 = (const float*)d_in[3];
    const float* bhh0 = (const float*)d_in[4];
    const float* Wih1 = (const float*)d_in[5];
    const float* Whh1 = (const float*)d_in[6];
    const float* bih1 = (const float*)d_in[7];
    const float* bhh1 = (const float*)d_in[8];
    const float* fcW1 = (const float*)d_in[9];
    const float* fcb1 = (const float*)d_in[10];
    const float* fcW2 = (const float*)d_in[11];
    const float* fcb2 = (const float*)d_in[12];
    float* out = (float*)d_out;

    // ---- workspace layout ----
    char* wsp = (char*)d_ws;
    float*  h1s    = (float*) (wsp + 0);
    float*  c1s    = (float*) (wsp + 4096);
    float*  h2s    = (float*) (wsp + 8192);
    float*  c2s    = (float*) (wsp + 12288);
    double* pooled = (double*)(wsp + 16384);          // 8 KB
    const size_t STATE_BYTES = 24576;

    // per-t ring bytes: h1 fp16 2*8*128*2 = 4096 ; xp fp32 2*8*512*4 = 32768
    static const int cands[] = {3200, 1600, 800, 400, 160, 80, 40, 8};
    int chunkT = 8;
    for (int i = 0; i < 8; ++i) {
        size_t need = STATE_BYTES + (size_t)36864 * (size_t)cands[i];
        if (need <= ws_size) { chunkT = cands[i]; break; }
    }
    const int nchunks = TT / chunkT;

    _Float16* h1ring = (_Float16*)(wsp + STATE_BYTES);
    float* xpring = (float*)(wsp + STATE_BYTES + (size_t)2 * BB * chunkT * HH * 2);

    // zero persistent state (h/c/pooled); ws is re-poisoned before every call
    hipMemsetAsync(d_ws, 0, STATE_BYTES, stream);

    // pipeline: slot c runs A(c) || B(c-1) || C(c-2)
    const int nslots = nchunks + 2;
    for (int c = 0; c < nslots; ++c) {
        lstm_slot_kernel<<<144, 256, 0, stream>>>(
            x, Wih0, Whh0, bih0, bhh0, Wih1, Whh1, bih1, bhh1,
            h1s, c1s, h2s, c2s, pooled, h1ring, xpring,
            c, chunkT, nchunks);
    }
    head_kernel<<<BB, 128, 0, stream>>>(pooled, fcW1, fcb1, fcW2, fcb2, out);
}

// Round 7
// 62783.130 us; speedup vs baseline: 1.3467x; 1.0382x over previous
//
#include <hip/hip_runtime.h>

#define HH 128      // hidden size
#define G4 512      // 4*HH gates
#define TT 102400   // sequence length
#define BB 8        // batch

typedef _Float16 v2h __attribute__((ext_vector_type(2)));

#if __has_builtin(__builtin_amdgcn_fdot2)
#define FDOT2(a, b, c) __builtin_amdgcn_fdot2((a), (b), (c), false)
#else
static __device__ __forceinline__ float fdot2_fb(v2h a, v2h b, float c) {
    return fmaf((float)a[0], (float)b[0], fmaf((float)a[1], (float)b[1], c));
}
#define FDOT2(a, b, c) fdot2_fb((a), (b), (c))
#endif

// DPP lane move (VALU pipe): 0xB1=xor1(quad), 0x4E=xor2(quad), 0x141=xor7(row-half mirror)
template<int CTRL>
__device__ __forceinline__ float dpp_mov(float v) {
    return __int_as_float(
        __builtin_amdgcn_update_dpp(0, __float_as_int(v), CTRL, 0xF, 0xF, true));
}

__device__ __forceinline__ float tanh_f(float x) {
    return fmaf(2.0f, __builtin_amdgcn_rcpf(1.0f + __expf(-2.0f * x)), -1.0f);
}

union HI { int i; v2h h; };

// ---------------------------------------------------------------------------
// 8-lane group math: group Q owns cells {2Q,2Q+1}; lane j covers k in
// [16j,16j+16) of all 8 gate rows (rho: bit0=cell, bits2:1=gate).
// dotred: partial dots + reduce-to-distinct. Keep-functionals (GF(2)):
//   round1 mask1: phi1 = j0^j2  (phi1*1=1, *2=0, *7=0)
//   round2 mask2: phi2 = j0^j1  (phi2*2=1, *7=0)   <- R6 bug: used j1 (j1*7=1!)
//   round3 mask7: phi3 = j2
// Lane j ends with FULL 128-dot of row (cell=j0^j2, gate=2*(j0^j1)+j2).
// Bijection: cell0 {i@0,f@7,g@2,o@5}, cell1 {i@3,f@4,g@1,o@6}.
// ---------------------------------------------------------------------------
__device__ __forceinline__ float dotred(const v2h w[8][8],
                                        const _Float16* __restrict__ hsl,
                                        bool bp1, bool bp2, bool bp3) {
    const int4* hp4 = (const int4*)hsl;     // 2x ds_read_b128 (16 halfs)
    int4 ha = hp4[0], hb = hp4[1];
    int hp[8] = {ha.x, ha.y, ha.z, ha.w, hb.x, hb.y, hb.z, hb.w};
    float acc[8];
#pragma unroll
    for (int r = 0; r < 8; ++r) acc[r] = 0.f;
#pragma unroll
    for (int i = 0; i < 8; ++i) {
        HI u; u.i = hp[i];
#pragma unroll
        for (int r = 0; r < 8; ++r) acc[r] = FDOT2(w[r][i], u.h, acc[r]);
    }
    // round 1 (mask 1): reduce cell bit; keep rho0 == bp1
    float b0[4];
#pragma unroll
    for (int m = 0; m < 4; ++m) {
        float send = bp1 ? acc[2 * m] : acc[2 * m + 1];
        float keep = bp1 ? acc[2 * m + 1] : acc[2 * m];
        b0[m] = keep + dpp_mov<0xB1>(send);
    }
    // round 2 (mask 2): reduce gate-hi bit; keep g1 == bp2 (= j0^j1)
    float d0[2];
#pragma unroll
    for (int i = 0; i < 2; ++i) {
        float send = bp2 ? b0[i] : b0[i + 2];
        float keep = bp2 ? b0[i + 2] : b0[i];
        d0[i] = keep + dpp_mov<0x4E>(send);
    }
    // round 3 (mask 7): reduce gate-lo bit; keep g0 == bp3 (= j2)
    float send = bp3 ? d0[0] : d0[1];
    float keep = bp3 ? d0[1] : d0[0];
    return keep + dpp_mov<0x141>(send);
}

// load this lane's fp16 weight slices: rows rho=0..7 -> W row 2Q+(rho&1)+128*(rho>>1)
__device__ __forceinline__ void load_w8h(const float* __restrict__ W,
                                         int Q, int j, v2h w[8][8]) {
#pragma unroll
    for (int r = 0; r < 8; ++r) {
        int row = 2 * Q + (r & 1) + 128 * (r >> 1);
        const float4* rp = (const float4*)(W + (size_t)row * HH + 16 * j);
#pragma unroll
        for (int i = 0; i < 4; ++i) {
            float4 f = rp[i];
            w[r][2 * i]     = (v2h){(_Float16)f.x, (_Float16)f.y};
            w[r][2 * i + 1] = (v2h){(_Float16)f.z, (_Float16)f.w};
        }
    }
}

// ---------------------------------------------------------------------------
// One pipeline slot (512 threads/block):
//   blocks 0..7  = stage A (layer0 chain, chunk c)
//   blocks 8..15 = stage C (layer1 chain, chunk c-2)
//   blocks 16..79= stage B (xp1 GEMM, chunk c-1): 8 batch x 8 t-slice
// Stages independent within a launch; stream order gives producer->consumer
// ordering across launches.
// ---------------------------------------------------------------------------
__global__ void __launch_bounds__(512, 2)
lstm_slot_kernel(
    const float* __restrict__ x,
    const float* __restrict__ Wih0, const float* __restrict__ Whh0,
    const float* __restrict__ bih0, const float* __restrict__ bhh0,
    const float* __restrict__ Wih1, const float* __restrict__ Whh1,
    const float* __restrict__ bih1, const float* __restrict__ bhh1,
    float* __restrict__ h1s, float* __restrict__ c1s,
    float* __restrict__ h2s, float* __restrict__ c2s,
    double* __restrict__ pooled,
    _Float16* __restrict__ h1ring,  // [2][B][chunkT][HH]   fp16
    float* __restrict__ xpring,     // [2][B][chunkT][HH][4] (t,cell,gate) fp32
    int c, int chunkT, int nchunks)
{
    __shared__ __align__(32) _Float16 hh[2 * HH];
    const int t = threadIdx.x;
    const int Q = t >> 3;                 // 8-lane group -> cells {2Q, 2Q+1}
    const int j = t & 7;
    const bool bp1 = ((j ^ (j >> 2)) & 1) != 0;   // phi1 = j0^j2 (cell bit)
    const bool bp2 = ((j ^ (j >> 1)) & 1) != 0;   // phi2 = j0^j1 (gate hi)  [FIXED]
    const bool bp3 = ((j >> 2) & 1) != 0;         // phi3 = j2    (gate lo)
    const int cellj = bp1 ? 1 : 0;
    const int gatej = (bp2 ? 2 : 0) + (bp3 ? 1 : 0);
    const int myc   = 2 * Q + cellj;
    const int myrow = myc + 128 * gatej;
    const bool owner = (gatej == 0);              // gate-i lanes: j in {0,3}
    // branchless activation constants: sigmoid for i,f,o; tanh for g(=gate2)
    const bool isg = (gatej == 2);
    const float fe = isg ? -2.f : -1.f;
    const float fm = isg ?  2.f :  1.f;
    const float fa = isg ? -1.f :  0.f;

    if (blockIdx.x < 16) {
        // =============== chain stages (A: layer0, C: layer1) ===============
        const bool isA = (blockIdx.x < 8);
        const int cc = isA ? c : (c - 2);
        if (cc < 0 || cc >= nchunks) return;
        const int b = blockIdx.x & 7;

        v2h w[8][8];
        load_w8h(isA ? Whh0 : Whh1, Q, j, w);
        float bias_l = 0.f, wih_l = 0.f;
        if (isA) { bias_l = bih0[myrow] + bhh0[myrow]; wih_l = Wih0[myrow]; }

        float* hst = isA ? h1s : h2s;
        float* cst = isA ? c1s : c2s;
        float c_reg = cst[b * HH + myc];
        if (t < HH) hh[t] = (_Float16)hst[b * HH + t];

        _Float16* ringp = h1ring + ((size_t)((c & 1) * BB + b)) * (size_t)chunkT * HH;
        const float4* xb4 = (const float4*)(x + (size_t)b * TT + (size_t)cc * chunkT);
        const float* xps = xpring
            + ((size_t)((cc & 1) * BB + b)) * (size_t)chunkT * G4 + 4 * myc + gatej;

        const int nt4 = chunkT >> 2;
        float4 xq = {0, 0, 0, 0};
        float xpc[4] = {0, 0, 0, 0};
        if (isA) xq = xb4[0];
        else {
#pragma unroll
            for (int u = 0; u < 4; ++u) xpc[u] = xps[(size_t)u * G4];
        }
        double pacc = 0.0;
        float hfin = 0.f;
        __syncthreads();

        for (int t4 = 0; t4 < nt4; ++t4) {
            float4 xqn = {0, 0, 0, 0};
            float xpn[4] = {0, 0, 0, 0};
            if (isA) {
                if (t4 + 1 < nt4) xqn = xb4[t4 + 1];
            } else if (t4 + 1 < nt4) {
#pragma unroll
                for (int u = 0; u < 4; ++u)
                    xpn[u] = xps[(size_t)(t4 * 4 + 4 + u) * G4];
            }
#pragma unroll
            for (int u = 0; u < 4; ++u) {
                const int buf = u & 1;                 // static step parity
                float sfin = dotred(w, hh + buf * HH + 16 * j, bp1, bp2, bp3);
                float pre;
                if (isA) {
                    float xt = (u == 0) ? xq.x : (u == 1) ? xq.y
                             : (u == 2) ? xq.z : xq.w;
                    pre = fmaf(xt, wih_l, sfin + bias_l);
                } else {
                    pre = sfin + xpc[u];
                }
                // one activation per lane (its own gate)
                float e  = __expf(pre * fe);
                float rr = __builtin_amdgcn_rcpf(1.0f + e);
                float act = fmaf(fm, rr, fa);
                // gate-gather at owners (gate i): f@j^7, g@j^2, o@j^5
                float t1 = dpp_mov<0x141>(act);   // act[j^7] = f
                float t2 = dpp_mov<0x4E>(act);    // act[j^2] = g
                float t3 = dpp_mov<0x4E>(t1);     // act[j^5] = o
                c_reg = fmaf(t1, c_reg, act * t2);   // c = f*c + i*g
                float th = tanh_f(c_reg);
                float hv = t3 * th;                  // h = o*tanh(c)
                hfin = hv;
                if (owner) {
                    hh[(buf ^ 1) * HH + myc] = (_Float16)hv;
                    if (isA) ringp[(size_t)(t4 * 4 + u) * HH + myc] = (_Float16)hv;
                    else     pacc += (double)hv;
                }
                __syncthreads();
            }
            xq = xqn;
            if (!isA) {
#pragma unroll
                for (int u = 0; u < 4; ++u) xpc[u] = xpn[u];
            }
        }
        if (owner) {
            cst[b * HH + myc] = c_reg;
            hst[b * HH + myc] = hfin;
            if (!isA) pooled[b * HH + myc] += pacc;
        }

    } else {
        // ---------------- stage B: xp1 = Wih1 @ h1 + bias, chunk c-1 -------
        const int bc = c - 1;
        if (bc < 0 || bc >= nchunks) return;
        const int ib = blockIdx.x - 16;       // 0..63
        const int bb = ib >> 3;               // batch
        const int sl = ib & 7;                // t-slice (stride 8)
        v2h w[8][8];
        load_w8h(Wih1, Q, j, w);
        const float bias_l = bih1[myrow] + bhh1[myrow];
        const _Float16* hrp = h1ring
            + ((size_t)((bc & 1) * BB + bb)) * (size_t)chunkT * HH;
        float* xpw = xpring + ((size_t)((bc & 1) * BB + bb)) * (size_t)chunkT * G4;
        if (t < HH) hh[t] = hrp[(size_t)sl * HH + t];
        __syncthreads();
        int pb = 0;
        for (int tt = sl; tt < chunkT; tt += 8) {
            int ttn = tt + 8;
            bool pf = (t < HH) && (ttn < chunkT);
            _Float16 hn = (_Float16)0.f;
            if (pf) hn = hrp[(size_t)ttn * HH + t];          // prefetch
            float sfin = dotred(w, hh + pb * HH + 16 * j, bp1, bp2, bp3);
            if (pf) hh[(pb ^ 1) * HH + t] = hn;
            xpw[(size_t)tt * G4 + 4 * myc + gatej] = sfin + bias_l;
            __syncthreads();
            pb ^= 1;
        }
    }
}

// ---------------- head: mean-pool (done) -> FC+ReLU -> FC ------------------
__global__ void head_kernel(const double* __restrict__ pooled,
                            const float* __restrict__ fcW1, const float* __restrict__ fcb1,
                            const float* __restrict__ fcW2, const float* __restrict__ fcb2,
                            float* __restrict__ out)
{
    __shared__ float p_s[HH];
    __shared__ float hid_s[64];
    const int b = blockIdx.x, t = threadIdx.x;
    if (t < HH) p_s[t] = (float)(pooled[b * HH + t] * (1.0 / (double)TT));
    __syncthreads();
    if (t < 64) {
        float acc = fcb1[t];
#pragma unroll 8
        for (int k = 0; k < HH; ++k) acc = fmaf(p_s[k], fcW1[t * HH + k], acc);
        hid_s[t] = fmaxf(acc, 0.f);
    }
    __syncthreads();
    if (t < 11) {
        float acc = fcb2[t];
#pragma unroll
        for (int k = 0; k < 64; ++k) acc = fmaf(hid_s[k], fcW2[t * 64 + k], acc);
        out[b * 11 + t] = acc;
    }
}

// ---------------------------------------------------------------------------
extern "C" void kernel_launch(void* const* d_in, const int* in_sizes, int n_in,
                              void* d_out, int out_size, void* d_ws, size_t ws_size,
                              hipStream_t stream)
{
    const float* x    = (const float*)d_in[0];
    const float* Wih0 = (const float*)d_in[1];
    const float* Whh0 = (const float*)d_in[2];
    const float* bih0 = (const float*)d_in[3];
    const float* bhh0 = (const float*)d_in[4];
    const float* Wih1 = (const float*)d_in[5];
    const float* Whh1 = (const float*)d_in[6];
    const float* bih1 = (const float*)d_in[7];
    const float* bhh1 = (const float*)d_in[8];
    const float* fcW1 = (const float*)d_in[9];
    const float* fcb1 = (const float*)d_in[10];
    const float* fcW2 = (const float*)d_in[11];
    const float* fcb2 = (const float*)d_in[12];
    float* out = (float*)d_out;

    // ---- workspace layout ----
    char* wsp = (char*)d_ws;
    float*  h1s    = (float*) (wsp + 0);
    float*  c1s    = (float*) (wsp + 4096);
    float*  h2s    = (float*) (wsp + 8192);
    float*  c2s    = (float*) (wsp + 12288);
    double* pooled = (double*)(wsp + 16384);          // 8 KB
    const size_t STATE_BYTES = 24576;

    // per-t ring bytes: h1 fp16 2*8*128*2 = 4096 ; xp fp32 2*8*512*4 = 32768
    static const int cands[] = {3200, 1600, 800, 400, 160, 80, 40, 8};
    int chunkT = 8;
    for (int i = 0; i < 8; ++i) {
        size_t need = STATE_BYTES + (size_t)36864 * (size_t)cands[i];
        if (need <= ws_size) { chunkT = cands[i]; break; }
    }
    const int nchunks = TT / chunkT;

    _Float16* h1ring = (_Float16*)(wsp + STATE_BYTES);
    float* xpring = (float*)(wsp + STATE_BYTES + (size_t)2 * BB * chunkT * HH * 2);

    // zero persistent state (h/c/pooled); ws is re-poisoned before every call
    hipMemsetAsync(d_ws, 0, STATE_BYTES, stream);

    // pipeline: slot c runs A(c) || B(c-1) || C(c-2)
    const int nslots = nchunks + 2;
    for (int c = 0; c < nslots; ++c) {
        lstm_slot_kernel<<<80, 512, 0, stream>>>(
            x, Wih0, Whh0, bih0, bhh0, Wih1, Whh1, bih1, bhh1,
            h1s, c1s, h2s, c2s, pooled, h1ring, xpring,
            c, chunkT, nchunks);
    }
    head_kernel<<<BB, 128, 0, stream>>>(pooled, fcW1, fcb1, fcW2, fcb2, out);
}